// Round 23
// baseline (128.981 us; speedup 1.0000x reference)
//
#include <hip/hip_runtime.h>
#include <math.h>

#define N_ANCH 120000
#define N_CLS  80
#define TOPK   4096
#define MAXDET 100
#define CONF   0.25f
#define IOUT   0.4f
#define KEYCAP 30720   // candidate buffer capacity (expected K' ~ 4400)
#define PRETILES 8     // tiles with precomputed masks (NMS early-exits at ~2)

// ---------- helpers ----------
__device__ __forceinline__ unsigned f2ord(float f) {
    unsigned u = __float_as_uint(f);
    return (u & 0x80000000u) ? ~u : (u | 0x80000000u);
}
__device__ __forceinline__ float ord2f(unsigned o) {
    unsigned u = (o & 0x80000000u) ? (o & 0x7FFFFFFFu) : ~o;
    return __uint_as_float(u);
}
__device__ __forceinline__ unsigned long long shflx64(unsigned long long v, int m) {
    unsigned lo = (unsigned)__shfl_xor((int)(unsigned)v, m, 64);
    unsigned hi = (unsigned)__shfl_xor((int)(unsigned)(v >> 32), m, 64);
    return ((unsigned long long)hi << 32) | lo;
}
#define ORD_NEGINF 0x007FFFFFu   // f2ord(-INFINITY)
// Byte-swap bin remap (involution): consecutive logical bins -> 1KB apart.
#define BMAP(b) ((((b) & 0xFFu) << 8) | ((unsigned)(b) >> 8))

// offset box + area (exact reference op order: offset first, then area)
__device__ __forceinline__ void offbox(float4 c, int lb, float mc, float4* ob, float* ar) {
    float off = (float)lb * mc;
    float4 b;
    b.x = c.x + off; b.y = c.y + off; b.z = c.z + off; b.w = c.w + off;
    *ob = b;
    *ar = fmaxf(b.z - b.x, 0.f) * fmaxf(b.w - b.y, 0.f);
}
__device__ __forceinline__ float ioU(float4 bi, float ai, float4 bj, float aj) {
    float ix1 = fmaxf(bi.x, bj.x), iy1 = fmaxf(bi.y, bj.y);
    float ix2 = fminf(bi.z, bj.z), iy2 = fminf(bi.w, bj.w);
    float inter = fmaxf(ix2 - ix1, 0.f) * fmaxf(iy2 - iy1, 0.f);
    float uni = ai + aj - inter;
    return inter / fmaxf(uni, 1e-9f);
}

// ---------- 0: zero hist + meta (round-22 post-mortem: hipMemsetAsync's
// small-fill path costs ~41us flat; this kernel is ~3us) ----------
__global__ __launch_bounds__(1024) void k_zero(unsigned* hist, unsigned* meta) {
    int i = blockIdx.x * 1024 + threadIdx.x;
    if (i < 65536) hist[i] = 0u;
    if (i < 64) meta[i] = 0u;
}

// ---------- 1: decode, wave-per-anchor, FUSED histogram ----------
__global__ __launch_bounds__(256) void k_decode(const float* __restrict__ pred,
                                                unsigned* __restrict__ ord,
                                                int* __restrict__ lab,
                                                float4* __restrict__ box,
                                                unsigned* __restrict__ hist) {
    int wv = threadIdx.x >> 6, lane = threadIdx.x & 63;
    int a = blockIdx.x * 4 + wv;
    if (a >= N_ANCH) return;
    const float* p = pred + (long)a * 85;
    float v0 = p[lane];
    float v1 = (lane < 21) ? p[64 + lane] : 0.f;
    unsigned long long k0 = 0ull, k1 = 0ull;
    if (lane >= 5)
        k0 = ((unsigned long long)__float_as_uint(v0) << 32) | (0xFFFFFFFFu - (unsigned)(lane - 5));
    if (lane < 21)
        k1 = ((unsigned long long)__float_as_uint(v1) << 32) | (0xFFFFFFFFu - (unsigned)(59 + lane));
    unsigned long long key = k0 > k1 ? k0 : k1;
#pragma unroll
    for (int off = 1; off < 64; off <<= 1) {
        unsigned long long o = shflx64(key, off);
        if (o > key) key = o;
    }
    float best = __uint_as_float((unsigned)(key >> 32));
    int bl = (int)(0xFFFFFFFFu - (unsigned)(key & 0xFFFFFFFFu));
    float x = __shfl(v0, 0, 64), y = __shfl(v0, 1, 64);
    float w = __shfl(v0, 2, 64), h = __shfl(v0, 3, 64);
    float obj = __shfl(v0, 4, 64);
    if (lane == 0) {
        float sc = obj * best;
        bool valid = sc > CONF;
        float m = valid ? sc : -INFINITY;
        float hw = w * 0.5f, hh = h * 0.5f;
        float4 b;
        b.x = x - hw; b.y = y - hh; b.z = x + hw; b.w = y + hh;
        unsigned o = f2ord(m);
        ord[a] = o;
        lab[a] = bl;
        box[a] = b;
        if (valid) atomicAdd(&hist[BMAP(o >> 16)], 1u);
    }
}

// ---------- 2: unperm + select0 fused via last-block (64 blocks: fence cheap) ----------
__global__ __launch_bounds__(1024) void k_unpsel(const unsigned* __restrict__ hist,
                                                 unsigned* __restrict__ cnt,
                                                 unsigned* __restrict__ chunkSum,
                                                 unsigned* __restrict__ meta) {
    __shared__ unsigned part[1024];
    __shared__ bool isLast;
    int t = threadIdx.x;
    int b = blockIdx.x * 1024 + t;
    unsigned v = hist[BMAP(b)];
    cnt[b] = v;
    unsigned s = v;
#pragma unroll
    for (int off = 1; off < 64; off <<= 1) s += (unsigned)__shfl_xor((int)s, off, 64);
    if ((t & 63) == 0) chunkSum[b >> 6] = s;
    __syncthreads();
    if (t == 0) {
        __threadfence();             // release (64 total: acceptable)
        unsigned done = atomicAdd(&meta[32], 1u);
        isLast = (done == 63u);
    }
    __syncthreads();
    if (!isLast) return;
    __threadfence();                 // acquire
    part[t] = chunkSum[t];
    __syncthreads();
    for (int off = 1; off < 1024; off <<= 1) {
        unsigned pv = (t + off < 1024) ? part[t + off] : 0u;
        __syncthreads();
        part[t] += pv;
        __syncthreads();
    }
    unsigned incl = part[t];
    unsigned after = (t + 1 < 1024) ? part[t + 1] : 0u;
    if (after < (unsigned)TOPK && incl >= (unsigned)TOPK) {
        int base = t * 64;
        unsigned c64[64];
#pragma unroll
        for (int i = 0; i < 64; ++i) c64[i] = cnt[base + i];
        unsigned run = after;
        for (int i = 63; i >= 0; --i) {
            unsigned c = c64[i];
            if (run + c >= (unsigned)TOPK) { meta[0] = (unsigned)(base + i); break; }
            run += c;
        }
    }
    // meta[0] stays 0 if nvalid < TOPK (fallback: all anchors candidates)
}

// ---------- 3: compact all candidates with bin >= b1 (block-aggregated atomic) ----------
__global__ __launch_bounds__(256) void k_compact(const unsigned* __restrict__ ord,
                                                 unsigned* meta,
                                                 unsigned long long* __restrict__ keys) {
    __shared__ unsigned wc[4];
    __shared__ unsigned sBase;
    int a = blockIdx.x * 256 + threadIdx.x;
    int lane = threadIdx.x & 63, wv = threadIdx.x >> 6;
    unsigned b1 = meta[0];
    unsigned o = (a < N_ANCH) ? ord[a] : 0u;
    bool isC = (a < N_ANCH) && ((o >> 16) >= b1);
    unsigned long long bal = __ballot(isC);
    if (lane == 0) wc[wv] = (unsigned)__popcll(bal);
    __syncthreads();
    if (threadIdx.x == 0) {
        unsigned tg = wc[0] + wc[1] + wc[2] + wc[3];
        sBase = tg ? atomicAdd(&meta[6], tg) : 0u;
    }
    __syncthreads();
    unsigned long long ltmask = (lane == 63) ? ~0ull >> 1 : (1ull << lane) - 1ull;
    if (isC) {
        unsigned p = sBase;
        for (int w = 0; w < wv; ++w) p += wc[w];
        p += (unsigned)__popcll(bal & ltmask);
        if (p < KEYCAP) keys[p] = ((unsigned long long)o << 32) | (unsigned)(~(unsigned)a);
    }
}

// ---------- 4: RANK-SCATTER, wave-per-candidate, runtime K', block-reduced max ----------
__global__ __launch_bounds__(1024) void k_rank(const unsigned long long* __restrict__ keys,
                                               const int* __restrict__ lab,
                                               const float4* __restrict__ box,
                                               int* __restrict__ cIdx,
                                               float* __restrict__ cScore,
                                               int* __restrict__ cLab,
                                               float4* __restrict__ cBox,
                                               unsigned* meta) {
    __shared__ float smax[16];
    int wv = threadIdx.x >> 6, lane = threadIdx.x & 63;
    unsigned K = meta[6];
    if (K > KEYCAP) K = KEYCAP;
    int nw = (int)((K + 63) >> 6);
    float mymax = 0.f;
    for (int i = blockIdx.x * 16 + wv; i < (int)K; i += 256 * 16) {
        unsigned long long ki = keys[i];
        unsigned cnt = 0;
#pragma unroll 8
        for (int k = 0; k < nw; ++k) {
            int idx = (k << 6) + lane;
            unsigned long long kv = (idx < (int)K) ? keys[idx] : 0ull;
            cnt += (kv > ki) ? 1u : 0u;
        }
#pragma unroll
        for (int off = 1; off < 64; off <<= 1) cnt += (unsigned)__shfl_xor((int)cnt, off, 64);
        if (lane == 0 && cnt < (unsigned)TOPK) {
            int r = (int)cnt;
            unsigned o = (unsigned)(ki >> 32);
            unsigned a = ~(unsigned)(ki & 0xFFFFFFFFu);
            float sc = ord2f(o);
            cIdx[r] = (int)a;
            cScore[r] = sc;
            cLab[r] = lab[a];
            float4 b = box[a];
            cBox[r] = b;
            if (sc > CONF)
                mymax = fmaxf(mymax, fmaxf(0.f, fmaxf(fmaxf(b.x, b.y), fmaxf(b.z, b.w))));
        }
    }
    if (lane == 0) smax[wv] = mymax;
    __syncthreads();
    if (threadIdx.x == 0) {
        float m = 0.f;
#pragma unroll
        for (int q = 0; q < 16; ++q) m = fmaxf(m, smax[q]);
        if (m > 0.f) atomicMax(&meta[8], __float_as_uint(m));
    }
}

// ---------- 5: suppression bitmask, FIRST 512 ROWS ONLY (128 blocks) ----------
__global__ __launch_bounds__(256) void k_mask(const float4* __restrict__ cBox,
                                              const int* __restrict__ cLab,
                                              const unsigned* __restrict__ meta,
                                              unsigned long long* __restrict__ M,
                                              unsigned long long* __restrict__ Diag) {
    int lane = threadIdx.x & 63;
    int i = blockIdx.x * 4 + (threadIdx.x >> 6);     // 0..511
    float mc = __uint_as_float(meta[8]) + 1.0f;
    float4 bi; float ai;
    offbox(cBox[i], cLab[i], mc, &bi, &ai);          // broadcast loads
    int w0 = i >> 6;
    unsigned long long myWord = 0ull;
    for (int jw = w0; jw < 64; ++jw) {
        int j = (jw << 6) + lane;
        float4 bj; float aj;
        offbox(cBox[j], cLab[j], mc, &bj, &aj);      // coalesced
        bool bit = (j > i) & (ioU(bi, ai, bj, aj) > IOUT);
        unsigned long long word = __ballot(bit);
        if (lane == jw) myWord = word;
    }
    M[(long)i * 64 + lane] = myWord;
    if (lane == w0) Diag[i] = myWord;
}

// ---------- 6: greedy NMS (early-terminating) + finalize ----------
__global__ __launch_bounds__(256) void k_nmsfinal(const unsigned long long* __restrict__ M,
                                                  const unsigned long long* __restrict__ Diag,
                                                  const float* __restrict__ cScore,
                                                  const float4* __restrict__ cBox,
                                                  const int* __restrict__ cLab,
                                                  const int* __restrict__ cIdx,
                                                  const unsigned* __restrict__ meta,
                                                  const float* __restrict__ pred,
                                                  const int* __restrict__ img,
                                                  const int* __restrict__ inp,
                                                  float* __restrict__ out,
                                                  int out_size) {
    __shared__ unsigned long long keepW[64];
    __shared__ int sel[MAXDET];
    __shared__ int nsel;
    int t = threadIdx.x;
    int lane = t & 63;
    for (int i = t; i < out_size; i += 256) out[i] = 0.f;
    if (t == 0) nsel = 0;
    if (t < 64) {   // wave 0: NMS
        float mc = __uint_as_float(meta[8]) + 1.0f;
        unsigned long long S = 0ull;
#pragma unroll 8
        for (int b = 0; b < 64; ++b) {
            float sc = cScore[(b << 6) + lane];
            unsigned long long bal = __ballot(!(sc > CONF));
            if (lane == b) S = bal;
        }
        unsigned cntk = 0;
        int tstop = -1;
        unsigned long long ktStop = 0ull;
        for (int tt = 0; tt < 64; ++tt) {
            unsigned long long dcur;
            if (tt < PRETILES) {
                dcur = Diag[(tt << 6) + lane];
            } else {
                int j = (tt << 6) + lane;
                float4 bj; float aj;
                offbox(cBox[j], cLab[j], mc, &bj, &aj);
                dcur = 0ull;
                for (int r = 0; r < 64; ++r) {
                    int i = (tt << 6) + r;
                    float4 bi; float ai;
                    offbox(cBox[i], cLab[i], mc, &bi, &ai);   // broadcast
                    bool bit = (j > i) & (ioU(bi, ai, bj, aj) > IOUT);
                    unsigned long long word = __ballot(bit);
                    if (lane == r) dcur = word;
                }
            }
            unsigned long long s_tile =
                ((unsigned long long)(unsigned)__builtin_amdgcn_readlane((int)(unsigned)(S >> 32), tt)
                 << 32) |
                (unsigned)__builtin_amdgcn_readlane((int)(unsigned)S, tt);
#pragma unroll
            for (int b = 0; b < 64; ++b) {
                unsigned rl = (unsigned)__builtin_amdgcn_readlane((int)(unsigned)dcur, b);
                unsigned rh = (unsigned)__builtin_amdgcn_readlane((int)(unsigned)(dcur >> 32), b);
                unsigned long long row = ((unsigned long long)rh << 32) | rl;
                s_tile |= (((s_tile >> b) & 1ull) == 0ull) ? row : 0ull;
            }
            unsigned long long kt = ~s_tile;
            cntk += (unsigned)__popcll(kt);
            if (cntk >= MAXDET) { tstop = tt; ktStop = kt; break; }
            if (tt < PRETILES) {
                const unsigned long long* Mrow = M + (long)(tt << 6) * 64 + lane;
                unsigned long long a0 = 0, a1 = 0, a2 = 0, a3 = 0;
#pragma unroll
                for (int b = 0; b < 64; b += 4) {
                    a0 |= Mrow[(long)(b + 0) * 64] & (0ull - ((kt >> (b + 0)) & 1ull));
                    a1 |= Mrow[(long)(b + 1) * 64] & (0ull - ((kt >> (b + 1)) & 1ull));
                    a2 |= Mrow[(long)(b + 2) * 64] & (0ull - ((kt >> (b + 2)) & 1ull));
                    a3 |= Mrow[(long)(b + 3) * 64] & (0ull - ((kt >> (b + 3)) & 1ull));
                }
                S |= (a0 | a1) | (a2 | a3);
            } else {
                unsigned long long acc = 0ull;
                for (int b = 0; b < 64; ++b) {
                    if (!((kt >> b) & 1ull)) continue;
                    int i = (tt << 6) + b;
                    float4 bi; float ai;
                    offbox(cBox[i], cLab[i], mc, &bi, &ai);   // broadcast
                    unsigned long long w = 0ull;
                    for (int c2 = 0; c2 < 64; ++c2) {
                        int j = (lane << 6) + c2;
                        float4 bj; float aj;
                        offbox(cBox[j], cLab[j], mc, &bj, &aj);
                        bool bit = (j > i) & (ioU(bi, ai, bj, aj) > IOUT);
                        w |= ((unsigned long long)(bit ? 1 : 0)) << c2;
                    }
                    acc |= w;
                }
                S |= acc;
            }
        }
        if (tstop >= 0) {
            keepW[lane] = (lane < tstop) ? ~S : (lane == tstop ? ktStop : 0ull);
        } else {
            keepW[lane] = ~S;
        }
    }
    __syncthreads();
    if (t < 64) {   // rank kept candidates
        unsigned long long kw = keepW[t];
        int cntb = __popcll(kw);
        int incl = cntb;
        for (int off = 1; off < 64; off <<= 1) {
            int v = __shfl_up(incl, off);
            if (t >= off) incl += v;
        }
        int rk = incl - cntb;
        if (t == 63) nsel = (incl < MAXDET) ? incl : MAXDET;
        unsigned long long m = kw;
        while (m) {
            int b = __ffsll((unsigned long long)m) - 1;
            m &= m - 1;
            if (rk < MAXDET) sel[rk] = (t << 6) + b;
            ++rk;
        }
    }
    __syncthreads();
    int nk = nsel;
    int ih_i = img[0], iw_i = img[1];
    int nh_i = inp[0], nw_i = inp[1];
    if (iw_i == 0) iw_i = img[2];
    if (nw_i == 0) nw_i = inp[2];
    float ih = (float)ih_i, iw = (float)iw_i;
    float nh = (float)nh_i, nw = (float)nw_i;
    float gain = fminf(nh / ih, nw / iw);
    float pad0 = (nh - ih * gain) * 0.5f;
    float pad1 = (nw - iw * gain) * 0.5f;
    for (int o = t; o < nk; o += 256) {
        int k = sel[o];
        float4 b = cBox[k];
        float x1 = fminf(fmaxf((b.x - pad1) / gain, 0.f), iw);
        float y1 = fminf(fmaxf((b.y - pad0) / gain, 0.f), ih);
        float x2 = fminf(fmaxf((b.z - pad1) / gain, 0.f), iw);
        float y2 = fminf(fmaxf((b.w - pad0) / gain, 0.f), ih);
        out[o * 4 + 0] = (x1 + x2) * 0.5f / iw;
        out[o * 4 + 1] = (y1 + y2) * 0.5f / ih;
        out[o * 4 + 2] = (x2 - x1) / iw;
        out[o * 4 + 3] = (y2 - y1) / ih;
        out[4 * MAXDET + o] = cScore[k];
    }
    for (int p = t; p < nk * N_CLS; p += 256) {
        int o = p / N_CLS, c = p - o * N_CLS;
        int a = cIdx[sel[o]];
        out[5 * MAXDET + p] = pred[(long)a * 85 + 5 + c];
    }
}

extern "C" void kernel_launch(void* const* d_in, const int* in_sizes, int n_in,
                              void* d_out, int out_size, void* d_ws, size_t ws_size,
                              hipStream_t stream) {
    const float* pred = (const float*)d_in[0];
    const int* img = (const int*)d_in[1];
    const int* inp = (const int*)d_in[2];
    float* out = (float*)d_out;
    unsigned char* W = (unsigned char*)d_ws;

    unsigned* hist                = (unsigned*)(W + 0);                // 262144 B
    unsigned* meta                = (unsigned*)(W + 262144);           // 256 B
    unsigned* ord                 = (unsigned*)(W + 262400);           // 480000 B
    int* lab                      = (int*)(W + 742400);                // 480000 B
    float4* box                   = (float4*)(W + 1222400);            // 1920000 B
    unsigned long long* keys      = (unsigned long long*)(W + 3142400);// 245760 B (KEYCAP)
    unsigned long long* M         = (unsigned long long*)(W + 3388160);// 2097152 B (512 rows used)
    // Aliases into the dead ord region (ord unread after compact):
    unsigned long long* Diag      = (unsigned long long*)(W + 262400); // 32768 B
    int* cIdx                     = (int*)(W + 295168);                // 16384 B
    float* cScore                 = (float*)(W + 311552);              // 16384 B
    int* cLab                     = (int*)(W + 327936);                // 16384 B
    float4* cBox                  = (float4*)(W + 344320);             // 65536 B
    // Aliases into M (M written by k_mask AFTER cnt/chunkSum's last read):
    unsigned* cnt_lin             = (unsigned*)(W + 3388160);          // 262144 B
    unsigned* chunkSum            = (unsigned*)(W + 3650304);          // 4096 B

    int nb = (N_ANCH + 255) / 256;
    int nwb = (N_ANCH + 3) / 4;     // wave-per-anchor decode: 4 anchors/block
    k_zero<<<64, 1024, 0, stream>>>(hist, meta);
    k_decode<<<nwb, 256, 0, stream>>>(pred, ord, lab, box, hist);
    k_unpsel<<<64, 1024, 0, stream>>>(hist, cnt_lin, chunkSum, meta);
    k_compact<<<nb, 256, 0, stream>>>(ord, meta, keys);
    k_rank<<<256, 1024, 0, stream>>>(keys, lab, box, cIdx, cScore, cLab, cBox, meta);
    k_mask<<<PRETILES * 16, 256, 0, stream>>>(cBox, cLab, meta, M, Diag);
    k_nmsfinal<<<1, 256, 0, stream>>>(M, Diag, cScore, cBox, cLab, cIdx, meta,
                                      pred, img, inp, out, out_size);
}

// Round 24
// 128.517 us; speedup vs baseline: 1.0036x; 1.0036x over previous
//
#include <hip/hip_runtime.h>
#include <math.h>

#define N_ANCH 120000
#define N_CLS  80
#define TOPK   4096
#define MAXDET 100
#define CONF   0.25f
#define IOUT   0.4f
#define KEYCAP 30720   // candidate buffer capacity (expected K' ~ 4400)
#define PRETILES 8     // tiles with precomputed masks (NMS early-exits at ~2)

// ---------- helpers ----------
__device__ __forceinline__ unsigned f2ord(float f) {
    unsigned u = __float_as_uint(f);
    return (u & 0x80000000u) ? ~u : (u | 0x80000000u);
}
__device__ __forceinline__ float ord2f(unsigned o) {
    unsigned u = (o & 0x80000000u) ? (o & 0x7FFFFFFFu) : ~o;
    return __uint_as_float(u);
}
__device__ __forceinline__ unsigned long long shflx64(unsigned long long v, int m) {
    unsigned lo = (unsigned)__shfl_xor((int)(unsigned)v, m, 64);
    unsigned hi = (unsigned)__shfl_xor((int)(unsigned)(v >> 32), m, 64);
    return ((unsigned long long)hi << 32) | lo;
}
#define ORD_NEGINF 0x007FFFFFu   // f2ord(-INFINITY)
// Byte-swap bin remap (involution): consecutive logical bins -> 1KB apart.
#define BMAP(b) ((((b) & 0xFFu) << 8) | ((unsigned)(b) >> 8))

// offset box + area (exact reference op order: offset first, then area)
__device__ __forceinline__ void offbox(float4 c, int lb, float mc, float4* ob, float* ar) {
    float off = (float)lb * mc;
    float4 b;
    b.x = c.x + off; b.y = c.y + off; b.z = c.z + off; b.w = c.w + off;
    *ob = b;
    *ar = fmaxf(b.z - b.x, 0.f) * fmaxf(b.w - b.y, 0.f);
}
__device__ __forceinline__ float ioU(float4 bi, float ai, float4 bj, float aj) {
    float ix1 = fmaxf(bi.x, bj.x), iy1 = fmaxf(bi.y, bj.y);
    float ix2 = fminf(bi.z, bj.z), iy2 = fminf(bi.w, bj.w);
    float inter = fmaxf(ix2 - ix1, 0.f) * fmaxf(iy2 - iy1, 0.f);
    float uni = ai + aj - inter;
    return inter / fmaxf(uni, 1e-9f);
}

// ---------- 0: zero hist + meta ----------
__global__ __launch_bounds__(1024) void k_zero(unsigned* hist, unsigned* meta) {
    int i = blockIdx.x * 1024 + threadIdx.x;
    if (i < 65536) hist[i] = 0u;
    if (i < 64) meta[i] = 0u;
}

// ---------- 1: decode, wave-per-anchor, FUSED histogram ----------
__global__ __launch_bounds__(256) void k_decode(const float* __restrict__ pred,
                                                unsigned* __restrict__ ord,
                                                int* __restrict__ lab,
                                                float4* __restrict__ box,
                                                unsigned* __restrict__ hist) {
    int wv = threadIdx.x >> 6, lane = threadIdx.x & 63;
    int a = blockIdx.x * 4 + wv;
    if (a >= N_ANCH) return;
    const float* p = pred + (long)a * 85;
    float v0 = p[lane];
    float v1 = (lane < 21) ? p[64 + lane] : 0.f;
    unsigned long long k0 = 0ull, k1 = 0ull;
    if (lane >= 5)
        k0 = ((unsigned long long)__float_as_uint(v0) << 32) | (0xFFFFFFFFu - (unsigned)(lane - 5));
    if (lane < 21)
        k1 = ((unsigned long long)__float_as_uint(v1) << 32) | (0xFFFFFFFFu - (unsigned)(59 + lane));
    unsigned long long key = k0 > k1 ? k0 : k1;
#pragma unroll
    for (int off = 1; off < 64; off <<= 1) {
        unsigned long long o = shflx64(key, off);
        if (o > key) key = o;
    }
    float best = __uint_as_float((unsigned)(key >> 32));
    int bl = (int)(0xFFFFFFFFu - (unsigned)(key & 0xFFFFFFFFu));
    float x = __shfl(v0, 0, 64), y = __shfl(v0, 1, 64);
    float w = __shfl(v0, 2, 64), h = __shfl(v0, 3, 64);
    float obj = __shfl(v0, 4, 64);
    if (lane == 0) {
        float sc = obj * best;
        bool valid = sc > CONF;
        float m = valid ? sc : -INFINITY;
        float hw = w * 0.5f, hh = h * 0.5f;
        float4 b;
        b.x = x - hw; b.y = y - hh; b.z = x + hw; b.w = y + hh;
        unsigned o = f2ord(m);
        ord[a] = o;
        lab[a] = bl;
        box[a] = b;
        if (valid) atomicAdd(&hist[BMAP(o >> 16)], 1u);
    }
}

// ---------- 2: select0, SINGLE BLOCK, fence-free (fuses unperm+select0) ----------
// Round-23 post-mortem: the 64-block fence fusion cost ~12us (L2 writeback
// serialization); device fences always lose to plain launches on gfx950.
// One block reads all 65536 BMAP'd bins directly into registers (64/thread,
// unrolled static indices, deep-pipelined scattered loads), LDS suffix-scan,
// boundary thread reuses its registers. No fence, no extra kernel.
__global__ __launch_bounds__(1024) void k_selectall(const unsigned* __restrict__ hist,
                                                    unsigned* __restrict__ meta) {
    __shared__ unsigned part[1024];
    int t = threadIdx.x;
    int base = t * 64;
    unsigned c64[64];
#pragma unroll
    for (int i = 0; i < 64; ++i) c64[i] = hist[BMAP(base + i)];  // independent, pipelined
    unsigned local = 0;
#pragma unroll
    for (int i = 0; i < 64; ++i) local += c64[i];
    part[t] = local;
    __syncthreads();
    for (int off = 1; off < 1024; off <<= 1) {
        unsigned v = (t + off < 1024) ? part[t + off] : 0u;
        __syncthreads();
        part[t] += v;
        __syncthreads();
    }
    unsigned incl = part[t];
    unsigned after = (t + 1 < 1024) ? part[t + 1] : 0u;
    if (after < (unsigned)TOPK && incl >= (unsigned)TOPK) {
        unsigned run = after;
#pragma unroll
        for (int i = 63; i >= 0; --i) {
            if (run + c64[i] >= (unsigned)TOPK) { meta[0] = (unsigned)(base + i); break; }
            run += c64[i];
        }
    }
    // meta[0] stays 0 if nvalid < TOPK (fallback: all anchors candidates)
}

// ---------- 3: compact all candidates with bin >= b1 (block-aggregated atomic) ----------
__global__ __launch_bounds__(256) void k_compact(const unsigned* __restrict__ ord,
                                                 unsigned* meta,
                                                 unsigned long long* __restrict__ keys) {
    __shared__ unsigned wc[4];
    __shared__ unsigned sBase;
    int a = blockIdx.x * 256 + threadIdx.x;
    int lane = threadIdx.x & 63, wv = threadIdx.x >> 6;
    unsigned b1 = meta[0];
    unsigned o = (a < N_ANCH) ? ord[a] : 0u;
    bool isC = (a < N_ANCH) && ((o >> 16) >= b1);
    unsigned long long bal = __ballot(isC);
    if (lane == 0) wc[wv] = (unsigned)__popcll(bal);
    __syncthreads();
    if (threadIdx.x == 0) {
        unsigned tg = wc[0] + wc[1] + wc[2] + wc[3];
        sBase = tg ? atomicAdd(&meta[6], tg) : 0u;
    }
    __syncthreads();
    unsigned long long ltmask = (lane == 63) ? ~0ull >> 1 : (1ull << lane) - 1ull;
    if (isC) {
        unsigned p = sBase;
        for (int w = 0; w < wv; ++w) p += wc[w];
        p += (unsigned)__popcll(bal & ltmask);
        if (p < KEYCAP) keys[p] = ((unsigned long long)o << 32) | (unsigned)(~(unsigned)a);
    }
}

// ---------- 4: RANK-SCATTER, wave-per-candidate, runtime K', block-reduced max ----------
__global__ __launch_bounds__(1024) void k_rank(const unsigned long long* __restrict__ keys,
                                               const int* __restrict__ lab,
                                               const float4* __restrict__ box,
                                               int* __restrict__ cIdx,
                                               float* __restrict__ cScore,
                                               int* __restrict__ cLab,
                                               float4* __restrict__ cBox,
                                               unsigned* meta) {
    __shared__ float smax[16];
    int wv = threadIdx.x >> 6, lane = threadIdx.x & 63;
    unsigned K = meta[6];
    if (K > KEYCAP) K = KEYCAP;
    int nw = (int)((K + 63) >> 6);
    float mymax = 0.f;
    for (int i = blockIdx.x * 16 + wv; i < (int)K; i += 256 * 16) {
        unsigned long long ki = keys[i];
        unsigned cnt = 0;
#pragma unroll 8
        for (int k = 0; k < nw; ++k) {
            int idx = (k << 6) + lane;
            unsigned long long kv = (idx < (int)K) ? keys[idx] : 0ull;
            cnt += (kv > ki) ? 1u : 0u;
        }
#pragma unroll
        for (int off = 1; off < 64; off <<= 1) cnt += (unsigned)__shfl_xor((int)cnt, off, 64);
        if (lane == 0 && cnt < (unsigned)TOPK) {
            int r = (int)cnt;
            unsigned o = (unsigned)(ki >> 32);
            unsigned a = ~(unsigned)(ki & 0xFFFFFFFFu);
            float sc = ord2f(o);
            cIdx[r] = (int)a;
            cScore[r] = sc;
            cLab[r] = lab[a];
            float4 b = box[a];
            cBox[r] = b;
            if (sc > CONF)
                mymax = fmaxf(mymax, fmaxf(0.f, fmaxf(fmaxf(b.x, b.y), fmaxf(b.z, b.w))));
        }
    }
    if (lane == 0) smax[wv] = mymax;
    __syncthreads();
    if (threadIdx.x == 0) {
        float m = 0.f;
#pragma unroll
        for (int q = 0; q < 16; ++q) m = fmaxf(m, smax[q]);
        if (m > 0.f) atomicMax(&meta[8], __float_as_uint(m));
    }
}

// ---------- 5: suppression bitmask, FIRST 512 ROWS ONLY (128 blocks) ----------
__global__ __launch_bounds__(256) void k_mask(const float4* __restrict__ cBox,
                                              const int* __restrict__ cLab,
                                              const unsigned* __restrict__ meta,
                                              unsigned long long* __restrict__ M,
                                              unsigned long long* __restrict__ Diag) {
    int lane = threadIdx.x & 63;
    int i = blockIdx.x * 4 + (threadIdx.x >> 6);     // 0..511
    float mc = __uint_as_float(meta[8]) + 1.0f;
    float4 bi; float ai;
    offbox(cBox[i], cLab[i], mc, &bi, &ai);          // broadcast loads
    int w0 = i >> 6;
    unsigned long long myWord = 0ull;
    for (int jw = w0; jw < 64; ++jw) {
        int j = (jw << 6) + lane;
        float4 bj; float aj;
        offbox(cBox[j], cLab[j], mc, &bj, &aj);      // coalesced
        bool bit = (j > i) & (ioU(bi, ai, bj, aj) > IOUT);
        unsigned long long word = __ballot(bit);
        if (lane == jw) myWord = word;
    }
    M[(long)i * 64 + lane] = myWord;
    if (lane == w0) Diag[i] = myWord;
}

// ---------- 6: greedy NMS (early-terminating) + finalize ----------
__global__ __launch_bounds__(256) void k_nmsfinal(const unsigned long long* __restrict__ M,
                                                  const unsigned long long* __restrict__ Diag,
                                                  const float* __restrict__ cScore,
                                                  const float4* __restrict__ cBox,
                                                  const int* __restrict__ cLab,
                                                  const int* __restrict__ cIdx,
                                                  const unsigned* __restrict__ meta,
                                                  const float* __restrict__ pred,
                                                  const int* __restrict__ img,
                                                  const int* __restrict__ inp,
                                                  float* __restrict__ out,
                                                  int out_size) {
    __shared__ unsigned long long keepW[64];
    __shared__ int sel[MAXDET];
    __shared__ int nsel;
    int t = threadIdx.x;
    int lane = t & 63;
    for (int i = t; i < out_size; i += 256) out[i] = 0.f;
    if (t == 0) nsel = 0;
    if (t < 64) {   // wave 0: NMS
        float mc = __uint_as_float(meta[8]) + 1.0f;
        unsigned long long S = 0ull;
#pragma unroll 8
        for (int b = 0; b < 64; ++b) {
            float sc = cScore[(b << 6) + lane];
            unsigned long long bal = __ballot(!(sc > CONF));
            if (lane == b) S = bal;
        }
        unsigned cntk = 0;
        int tstop = -1;
        unsigned long long ktStop = 0ull;
        for (int tt = 0; tt < 64; ++tt) {
            unsigned long long dcur;
            if (tt < PRETILES) {
                dcur = Diag[(tt << 6) + lane];
            } else {
                int j = (tt << 6) + lane;
                float4 bj; float aj;
                offbox(cBox[j], cLab[j], mc, &bj, &aj);
                dcur = 0ull;
                for (int r = 0; r < 64; ++r) {
                    int i = (tt << 6) + r;
                    float4 bi; float ai;
                    offbox(cBox[i], cLab[i], mc, &bi, &ai);   // broadcast
                    bool bit = (j > i) & (ioU(bi, ai, bj, aj) > IOUT);
                    unsigned long long word = __ballot(bit);
                    if (lane == r) dcur = word;
                }
            }
            unsigned long long s_tile =
                ((unsigned long long)(unsigned)__builtin_amdgcn_readlane((int)(unsigned)(S >> 32), tt)
                 << 32) |
                (unsigned)__builtin_amdgcn_readlane((int)(unsigned)S, tt);
#pragma unroll
            for (int b = 0; b < 64; ++b) {
                unsigned rl = (unsigned)__builtin_amdgcn_readlane((int)(unsigned)dcur, b);
                unsigned rh = (unsigned)__builtin_amdgcn_readlane((int)(unsigned)(dcur >> 32), b);
                unsigned long long row = ((unsigned long long)rh << 32) | rl;
                s_tile |= (((s_tile >> b) & 1ull) == 0ull) ? row : 0ull;
            }
            unsigned long long kt = ~s_tile;
            cntk += (unsigned)__popcll(kt);
            if (cntk >= MAXDET) { tstop = tt; ktStop = kt; break; }
            if (tt < PRETILES) {
                const unsigned long long* Mrow = M + (long)(tt << 6) * 64 + lane;
                unsigned long long a0 = 0, a1 = 0, a2 = 0, a3 = 0;
#pragma unroll
                for (int b = 0; b < 64; b += 4) {
                    a0 |= Mrow[(long)(b + 0) * 64] & (0ull - ((kt >> (b + 0)) & 1ull));
                    a1 |= Mrow[(long)(b + 1) * 64] & (0ull - ((kt >> (b + 1)) & 1ull));
                    a2 |= Mrow[(long)(b + 2) * 64] & (0ull - ((kt >> (b + 2)) & 1ull));
                    a3 |= Mrow[(long)(b + 3) * 64] & (0ull - ((kt >> (b + 3)) & 1ull));
                }
                S |= (a0 | a1) | (a2 | a3);
            } else {
                unsigned long long acc = 0ull;
                for (int b = 0; b < 64; ++b) {
                    if (!((kt >> b) & 1ull)) continue;
                    int i = (tt << 6) + b;
                    float4 bi; float ai;
                    offbox(cBox[i], cLab[i], mc, &bi, &ai);   // broadcast
                    unsigned long long w = 0ull;
                    for (int c2 = 0; c2 < 64; ++c2) {
                        int j = (lane << 6) + c2;
                        float4 bj; float aj;
                        offbox(cBox[j], cLab[j], mc, &bj, &aj);
                        bool bit = (j > i) & (ioU(bi, ai, bj, aj) > IOUT);
                        w |= ((unsigned long long)(bit ? 1 : 0)) << c2;
                    }
                    acc |= w;
                }
                S |= acc;
            }
        }
        if (tstop >= 0) {
            keepW[lane] = (lane < tstop) ? ~S : (lane == tstop ? ktStop : 0ull);
        } else {
            keepW[lane] = ~S;
        }
    }
    __syncthreads();
    if (t < 64) {   // rank kept candidates
        unsigned long long kw = keepW[t];
        int cntb = __popcll(kw);
        int incl = cntb;
        for (int off = 1; off < 64; off <<= 1) {
            int v = __shfl_up(incl, off);
            if (t >= off) incl += v;
        }
        int rk = incl - cntb;
        if (t == 63) nsel = (incl < MAXDET) ? incl : MAXDET;
        unsigned long long m = kw;
        while (m) {
            int b = __ffsll((unsigned long long)m) - 1;
            m &= m - 1;
            if (rk < MAXDET) sel[rk] = (t << 6) + b;
            ++rk;
        }
    }
    __syncthreads();
    int nk = nsel;
    int ih_i = img[0], iw_i = img[1];
    int nh_i = inp[0], nw_i = inp[1];
    if (iw_i == 0) iw_i = img[2];
    if (nw_i == 0) nw_i = inp[2];
    float ih = (float)ih_i, iw = (float)iw_i;
    float nh = (float)nh_i, nw = (float)nw_i;
    float gain = fminf(nh / ih, nw / iw);
    float pad0 = (nh - ih * gain) * 0.5f;
    float pad1 = (nw - iw * gain) * 0.5f;
    for (int o = t; o < nk; o += 256) {
        int k = sel[o];
        float4 b = cBox[k];
        float x1 = fminf(fmaxf((b.x - pad1) / gain, 0.f), iw);
        float y1 = fminf(fmaxf((b.y - pad0) / gain, 0.f), ih);
        float x2 = fminf(fmaxf((b.z - pad1) / gain, 0.f), iw);
        float y2 = fminf(fmaxf((b.w - pad0) / gain, 0.f), ih);
        out[o * 4 + 0] = (x1 + x2) * 0.5f / iw;
        out[o * 4 + 1] = (y1 + y2) * 0.5f / ih;
        out[o * 4 + 2] = (x2 - x1) / iw;
        out[o * 4 + 3] = (y2 - y1) / ih;
        out[4 * MAXDET + o] = cScore[k];
    }
    for (int p = t; p < nk * N_CLS; p += 256) {
        int o = p / N_CLS, c = p - o * N_CLS;
        int a = cIdx[sel[o]];
        out[5 * MAXDET + p] = pred[(long)a * 85 + 5 + c];
    }
}

extern "C" void kernel_launch(void* const* d_in, const int* in_sizes, int n_in,
                              void* d_out, int out_size, void* d_ws, size_t ws_size,
                              hipStream_t stream) {
    const float* pred = (const float*)d_in[0];
    const int* img = (const int*)d_in[1];
    const int* inp = (const int*)d_in[2];
    float* out = (float*)d_out;
    unsigned char* W = (unsigned char*)d_ws;

    unsigned* hist                = (unsigned*)(W + 0);                // 262144 B
    unsigned* meta                = (unsigned*)(W + 262144);           // 256 B
    unsigned* ord                 = (unsigned*)(W + 262400);           // 480000 B
    int* lab                      = (int*)(W + 742400);                // 480000 B
    float4* box                   = (float4*)(W + 1222400);            // 1920000 B
    unsigned long long* keys      = (unsigned long long*)(W + 3142400);// 245760 B (KEYCAP)
    unsigned long long* M         = (unsigned long long*)(W + 3388160);// 2097152 B (512 rows used)
    // Aliases into the dead ord region (ord unread after compact):
    unsigned long long* Diag      = (unsigned long long*)(W + 262400); // 32768 B
    int* cIdx                     = (int*)(W + 295168);                // 16384 B
    float* cScore                 = (float*)(W + 311552);              // 16384 B
    int* cLab                     = (int*)(W + 327936);                // 16384 B
    float4* cBox                  = (float4*)(W + 344320);             // 65536 B

    int nb = (N_ANCH + 255) / 256;
    int nwb = (N_ANCH + 3) / 4;     // wave-per-anchor decode: 4 anchors/block
    k_zero<<<64, 1024, 0, stream>>>(hist, meta);
    k_decode<<<nwb, 256, 0, stream>>>(pred, ord, lab, box, hist);
    k_selectall<<<1, 1024, 0, stream>>>(hist, meta);
    k_compact<<<nb, 256, 0, stream>>>(ord, meta, keys);
    k_rank<<<256, 1024, 0, stream>>>(keys, lab, box, cIdx, cScore, cLab, cBox, meta);
    k_mask<<<PRETILES * 16, 256, 0, stream>>>(cBox, cLab, meta, M, Diag);
    k_nmsfinal<<<1, 256, 0, stream>>>(M, Diag, cScore, cBox, cLab, cIdx, meta,
                                      pred, img, inp, out, out_size);
}

// Round 25
// 114.689 us; speedup vs baseline: 1.1246x; 1.1206x over previous
//
#include <hip/hip_runtime.h>
#include <math.h>

#define N_ANCH 120000
#define N_CLS  80
#define TOPK   4096
#define MAXDET 100
#define CONF   0.25f
#define IOUT   0.4f
#define KEYCAP 30720   // candidate buffer capacity (expected K' ~ 4400)

// ---------- helpers ----------
__device__ __forceinline__ unsigned f2ord(float f) {
    unsigned u = __float_as_uint(f);
    return (u & 0x80000000u) ? ~u : (u | 0x80000000u);
}
__device__ __forceinline__ float ord2f(unsigned o) {
    unsigned u = (o & 0x80000000u) ? (o & 0x7FFFFFFFu) : ~o;
    return __uint_as_float(u);
}
__device__ __forceinline__ unsigned long long shflx64(unsigned long long v, int m) {
    unsigned lo = (unsigned)__shfl_xor((int)(unsigned)v, m, 64);
    unsigned hi = (unsigned)__shfl_xor((int)(unsigned)(v >> 32), m, 64);
    return ((unsigned long long)hi << 32) | lo;
}
#define ORD_NEGINF 0x007FFFFFu   // f2ord(-INFINITY)
// Byte-swap bin remap (involution): consecutive logical bins -> 1KB apart.
#define BMAP(b) ((((b) & 0xFFu) << 8) | ((unsigned)(b) >> 8))

// ---------- 0: zero hist + meta ----------
__global__ __launch_bounds__(1024) void k_zero(unsigned* hist, unsigned* meta) {
    int i = blockIdx.x * 1024 + threadIdx.x;
    if (i < 65536) hist[i] = 0u;
    if (i < 64) meta[i] = 0u;
}

// ---------- 1: decode, wave-per-anchor, FUSED histogram (valid anchors only) ----------
__global__ __launch_bounds__(256) void k_decode(const float* __restrict__ pred,
                                                unsigned* __restrict__ ord,
                                                int* __restrict__ lab,
                                                float4* __restrict__ box,
                                                unsigned* __restrict__ hist) {
    int wv = threadIdx.x >> 6, lane = threadIdx.x & 63;
    int a = blockIdx.x * 4 + wv;
    if (a >= N_ANCH) return;
    const float* p = pred + (long)a * 85;
    float v0 = p[lane];
    float v1 = (lane < 21) ? p[64 + lane] : 0.f;
    unsigned long long k0 = 0ull, k1 = 0ull;
    if (lane >= 5)
        k0 = ((unsigned long long)__float_as_uint(v0) << 32) | (0xFFFFFFFFu - (unsigned)(lane - 5));
    if (lane < 21)
        k1 = ((unsigned long long)__float_as_uint(v1) << 32) | (0xFFFFFFFFu - (unsigned)(59 + lane));
    unsigned long long key = k0 > k1 ? k0 : k1;
#pragma unroll
    for (int off = 1; off < 64; off <<= 1) {
        unsigned long long o = shflx64(key, off);
        if (o > key) key = o;
    }
    float best = __uint_as_float((unsigned)(key >> 32));
    int bl = (int)(0xFFFFFFFFu - (unsigned)(key & 0xFFFFFFFFu));
    float x = __shfl(v0, 0, 64), y = __shfl(v0, 1, 64);
    float w = __shfl(v0, 2, 64), h = __shfl(v0, 3, 64);
    float obj = __shfl(v0, 4, 64);
    if (lane == 0) {
        float sc = obj * best;
        bool valid = sc > CONF;
        float m = valid ? sc : -INFINITY;
        float hw = w * 0.5f, hh = h * 0.5f;
        float4 b;
        b.x = x - hw; b.y = y - hh; b.z = x + hw; b.w = y + hh;
        unsigned o = f2ord(m);
        ord[a] = o;
        lab[a] = bl;
        box[a] = b;
        if (valid) atomicAdd(&hist[BMAP(o >> 16)], 1u);
    }
}

// ---------- 1b: un-permute hist into linear copy + 64-bin chunk sums ----------
__global__ __launch_bounds__(1024) void k_unperm(const unsigned* __restrict__ hist,
                                                 unsigned* __restrict__ cnt,
                                                 unsigned* __restrict__ chunkSum) {
    int b = blockIdx.x * 1024 + threadIdx.x;
    unsigned v = hist[BMAP(b)];
    cnt[b] = v;
    unsigned s = v;
#pragma unroll
    for (int off = 1; off < 64; off <<= 1) s += (unsigned)__shfl_xor((int)s, off, 64);
    if ((threadIdx.x & 63) == 0) chunkSum[b >> 6] = s;
}

// ---------- 2: find boundary bin b1: suffix(bins > b1) < TOPK <= suffix(bins >= b1) ----------
__global__ __launch_bounds__(1024) void k_select0(const unsigned* __restrict__ cnt,
                                                  const unsigned* __restrict__ chunkSum,
                                                  unsigned* meta) {
    __shared__ unsigned part[1024];
    int t = threadIdx.x;
    part[t] = chunkSum[t];
    __syncthreads();
    for (int off = 1; off < 1024; off <<= 1) {
        unsigned v = (t + off < 1024) ? part[t + off] : 0u;
        __syncthreads();
        part[t] += v;
        __syncthreads();
    }
    unsigned incl = part[t];
    unsigned after = (t + 1 < 1024) ? part[t + 1] : 0u;
    if (after < (unsigned)TOPK && incl >= (unsigned)TOPK) {
        int base = t * 64;
        unsigned c64[64];
#pragma unroll
        for (int i = 0; i < 64; ++i) c64[i] = cnt[base + i];
        unsigned run = after;
        for (int i = 63; i >= 0; --i) {
            unsigned c = c64[i];
            if (run + c >= (unsigned)TOPK) { meta[0] = (unsigned)(base + i); break; }
            run += c;
        }
    }
}

// ---------- 3: compact all candidates with bin >= b1 (block-aggregated atomic) ----------
__global__ __launch_bounds__(256) void k_compact(const unsigned* __restrict__ ord,
                                                 unsigned* meta,
                                                 unsigned long long* __restrict__ keys) {
    __shared__ unsigned wc[4];
    __shared__ unsigned sBase;
    int a = blockIdx.x * 256 + threadIdx.x;
    int lane = threadIdx.x & 63, wv = threadIdx.x >> 6;
    unsigned b1 = meta[0];
    unsigned o = (a < N_ANCH) ? ord[a] : 0u;
    bool isC = (a < N_ANCH) && ((o >> 16) >= b1);   // b1 > 0x7F normally -> -inf auto-excluded
    unsigned long long bal = __ballot(isC);
    if (lane == 0) wc[wv] = (unsigned)__popcll(bal);
    __syncthreads();
    if (threadIdx.x == 0) {
        unsigned tg = wc[0] + wc[1] + wc[2] + wc[3];
        sBase = tg ? atomicAdd(&meta[6], tg) : 0u;
    }
    __syncthreads();
    unsigned long long ltmask = (lane == 63) ? ~0ull >> 1 : (1ull << lane) - 1ull;
    if (isC) {
        unsigned p = sBase;
        for (int w = 0; w < wv; ++w) p += wc[w];
        p += (unsigned)__popcll(bal & ltmask);
        if (p < KEYCAP) keys[p] = ((unsigned long long)o << 32) | (unsigned)(~(unsigned)a);
    }
}

// ---------- 4: RANK-SCATTER, wave-per-candidate, runtime K', block-reduced max ----------
__global__ __launch_bounds__(1024) void k_rank(const unsigned long long* __restrict__ keys,
                                               const int* __restrict__ lab,
                                               const float4* __restrict__ box,
                                               int* __restrict__ cIdx,
                                               float* __restrict__ cScore,
                                               int* __restrict__ cLab,
                                               float4* __restrict__ cBox,
                                               unsigned* meta) {
    __shared__ float smax[16];
    int wv = threadIdx.x >> 6, lane = threadIdx.x & 63;
    unsigned K = meta[6];
    if (K > KEYCAP) K = KEYCAP;
    int nw = (int)((K + 63) >> 6);
    float mymax = 0.f;
    for (int i = blockIdx.x * 16 + wv; i < (int)K; i += 256 * 16) {
        unsigned long long ki = keys[i];        // wave-uniform broadcast
        unsigned cnt = 0;
#pragma unroll 8
        for (int k = 0; k < nw; ++k) {
            int idx = (k << 6) + lane;
            unsigned long long kv = (idx < (int)K) ? keys[idx] : 0ull;  // coalesced
            cnt += (kv > ki) ? 1u : 0u;
        }
#pragma unroll
        for (int off = 1; off < 64; off <<= 1) cnt += (unsigned)__shfl_xor((int)cnt, off, 64);
        if (lane == 0 && cnt < (unsigned)TOPK) {
            int r = (int)cnt;                   // unique descending rank
            unsigned o = (unsigned)(ki >> 32);
            unsigned a = ~(unsigned)(ki & 0xFFFFFFFFu);
            float sc = ord2f(o);
            cIdx[r] = (int)a;
            cScore[r] = sc;
            cLab[r] = lab[a];
            float4 b = box[a];
            cBox[r] = b;
            if (sc > CONF)
                mymax = fmaxf(mymax, fmaxf(0.f, fmaxf(fmaxf(b.x, b.y), fmaxf(b.z, b.w))));
        }
    }
    if (lane == 0) smax[wv] = mymax;
    __syncthreads();
    if (threadIdx.x == 0) {
        float m = 0.f;
#pragma unroll
        for (int q = 0; q < 16; ++q) m = fmaxf(m, smax[q]);
        if (m > 0.f) atomicMax(&meta[8], __float_as_uint(m));
    }
}

// ---------- 5: suppression bitmask, ballot form, FUSED offset-box compute ----------
__global__ __launch_bounds__(256) void k_mask(const float4* __restrict__ cBox,
                                              const int* __restrict__ cLab,
                                              const unsigned* __restrict__ meta,
                                              unsigned long long* __restrict__ M,
                                              unsigned long long* __restrict__ Diag) {
    int lane = threadIdx.x & 63;
    int i = blockIdx.x * 4 + (threadIdx.x >> 6);
    float mc = __uint_as_float(meta[8]) + 1.0f;
    float4 b = cBox[i];                     // broadcast
    float offi = (float)cLab[i] * mc;
    float4 bi;
    bi.x = b.x + offi; bi.y = b.y + offi; bi.z = b.z + offi; bi.w = b.w + offi;
    float ai = fmaxf(bi.z - bi.x, 0.f) * fmaxf(bi.w - bi.y, 0.f);
    int w0 = i >> 6;
    unsigned long long myWord = 0ull;
    for (int jw = w0; jw < 64; ++jw) {
        int j = (jw << 6) + lane;
        float4 c = cBox[j];                 // coalesced
        float offj = (float)cLab[j] * mc;   // coalesced
        float4 bj;
        bj.x = c.x + offj; bj.y = c.y + offj; bj.z = c.z + offj; bj.w = c.w + offj;
        float aj = fmaxf(bj.z - bj.x, 0.f) * fmaxf(bj.w - bj.y, 0.f);
        float ix1 = fmaxf(bi.x, bj.x), iy1 = fmaxf(bi.y, bj.y);
        float ix2 = fminf(bi.z, bj.z), iy2 = fminf(bi.w, bj.w);
        float inter = fmaxf(ix2 - ix1, 0.f) * fmaxf(iy2 - iy1, 0.f);
        float uni = ai + aj - inter;
        float iou = inter / fmaxf(uni, 1e-9f);
        bool bit = (j > i) & (iou > IOUT);
        unsigned long long word = __ballot(bit);
        if (lane == jw) myWord = word;
    }
    M[(long)i * 64 + lane] = myWord;
    if (lane == w0) Diag[i] = myWord;
}

// ---------- 6: greedy NMS (wave 0, early-terminating) + finalize, FUSED ----------
__global__ __launch_bounds__(256) void k_nmsfinal(const unsigned long long* __restrict__ M,
                                                  const unsigned long long* __restrict__ Diag,
                                                  const float* __restrict__ cScore,
                                                  const float4* __restrict__ cBox,
                                                  const int* __restrict__ cIdx,
                                                  const float* __restrict__ pred,
                                                  const int* __restrict__ img,
                                                  const int* __restrict__ inp,
                                                  float* __restrict__ out,
                                                  int out_size) {
    __shared__ unsigned long long keepW[64];
    __shared__ int sel[MAXDET];
    __shared__ int nsel;
    int t = threadIdx.x;
    int lane = t & 63;
    for (int i = t; i < out_size; i += 256) out[i] = 0.f;
    if (t == 0) nsel = 0;
    if (t < 64) {   // wave 0: NMS
        unsigned long long S = 0ull;
#pragma unroll 8
        for (int b = 0; b < 64; ++b) {
            float sc = cScore[(b << 6) + lane];
            unsigned long long bal = __ballot(!(sc > CONF));
            if (lane == b) S = bal;
        }
        unsigned long long d0 = Diag[lane];
        unsigned long long d1 = Diag[64 + lane];
        unsigned cntk = 0;
        int tstop = -1;
        unsigned long long ktStop = 0ull;
        for (int tt = 0; tt < 64; ++tt) {
            unsigned long long dcur = d0;
            d0 = d1;
            if (tt + 2 < 64) d1 = Diag[(tt + 2) * 64 + lane];
            unsigned long long s_tile =
                ((unsigned long long)(unsigned)__builtin_amdgcn_readlane((int)(unsigned)(S >> 32), tt)
                 << 32) |
                (unsigned)__builtin_amdgcn_readlane((int)(unsigned)S, tt);
#pragma unroll
            for (int b = 0; b < 64; ++b) {
                unsigned rl = (unsigned)__builtin_amdgcn_readlane((int)(unsigned)dcur, b);
                unsigned rh = (unsigned)__builtin_amdgcn_readlane((int)(unsigned)(dcur >> 32), b);
                unsigned long long row = ((unsigned long long)rh << 32) | rl;
                s_tile |= (((s_tile >> b) & 1ull) == 0ull) ? row : 0ull;
            }
            unsigned long long kt = ~s_tile;
            cntk += (unsigned)__popcll(kt);
            if (cntk >= MAXDET) { tstop = tt; ktStop = kt; break; }
            const unsigned long long* Mrow = M + (long)(tt << 6) * 64 + lane;
            unsigned long long a0 = 0, a1 = 0, a2 = 0, a3 = 0;
#pragma unroll
            for (int b = 0; b < 64; b += 4) {
                a0 |= Mrow[(long)(b + 0) * 64] & (0ull - ((kt >> (b + 0)) & 1ull));
                a1 |= Mrow[(long)(b + 1) * 64] & (0ull - ((kt >> (b + 1)) & 1ull));
                a2 |= Mrow[(long)(b + 2) * 64] & (0ull - ((kt >> (b + 2)) & 1ull));
                a3 |= Mrow[(long)(b + 3) * 64] & (0ull - ((kt >> (b + 3)) & 1ull));
            }
            S |= (a0 | a1) | (a2 | a3);
        }
        if (tstop >= 0) {
            keepW[lane] = (lane < tstop) ? ~S : (lane == tstop ? ktStop : 0ull);
        } else {
            keepW[lane] = ~S;
        }
    }
    __syncthreads();
    if (t < 64) {   // rank kept candidates
        unsigned long long kw = keepW[t];
        int cntb = __popcll(kw);
        int incl = cntb;
        for (int off = 1; off < 64; off <<= 1) {
            int v = __shfl_up(incl, off);
            if (t >= off) incl += v;
        }
        int rk = incl - cntb;
        if (t == 63) nsel = (incl < MAXDET) ? incl : MAXDET;
        unsigned long long m = kw;
        while (m) {
            int b = __ffsll((unsigned long long)m) - 1;
            m &= m - 1;
            if (rk < MAXDET) sel[rk] = (t << 6) + b;
            ++rk;
        }
    }
    __syncthreads();
    int nk = nsel;
    int ih_i = img[0], iw_i = img[1];
    int nh_i = inp[0], nw_i = inp[1];
    if (iw_i == 0) iw_i = img[2];
    if (nw_i == 0) nw_i = inp[2];
    float ih = (float)ih_i, iw = (float)iw_i;
    float nh = (float)nh_i, nw = (float)nw_i;
    float gain = fminf(nh / ih, nw / iw);
    float pad0 = (nh - ih * gain) * 0.5f;
    float pad1 = (nw - iw * gain) * 0.5f;
    for (int o = t; o < nk; o += 256) {
        int k = sel[o];
        float4 b = cBox[k];
        float x1 = fminf(fmaxf((b.x - pad1) / gain, 0.f), iw);
        float y1 = fminf(fmaxf((b.y - pad0) / gain, 0.f), ih);
        float x2 = fminf(fmaxf((b.z - pad1) / gain, 0.f), iw);
        float y2 = fminf(fmaxf((b.w - pad0) / gain, 0.f), ih);
        out[o * 4 + 0] = (x1 + x2) * 0.5f / iw;
        out[o * 4 + 1] = (y1 + y2) * 0.5f / ih;
        out[o * 4 + 2] = (x2 - x1) / iw;
        out[o * 4 + 3] = (y2 - y1) / ih;
        out[4 * MAXDET + o] = cScore[k];
    }
    for (int p = t; p < nk * N_CLS; p += 256) {
        int o = p / N_CLS, c = p - o * N_CLS;
        int a = cIdx[sel[o]];
        out[5 * MAXDET + p] = pred[(long)a * 85 + 5 + c];
    }
}

extern "C" void kernel_launch(void* const* d_in, const int* in_sizes, int n_in,
                              void* d_out, int out_size, void* d_ws, size_t ws_size,
                              hipStream_t stream) {
    const float* pred = (const float*)d_in[0];
    const int* img = (const int*)d_in[1];
    const int* inp = (const int*)d_in[2];
    float* out = (float*)d_out;
    unsigned char* W = (unsigned char*)d_ws;

    unsigned* hist                = (unsigned*)(W + 0);                // 262144 B
    unsigned* meta                = (unsigned*)(W + 262144);           // 256 B
    unsigned* ord                 = (unsigned*)(W + 262400);           // 480000 B
    int* lab                      = (int*)(W + 742400);                // 480000 B
    float4* box                   = (float4*)(W + 1222400);            // 1920000 B
    unsigned long long* keys      = (unsigned long long*)(W + 3142400);// 245760 B (KEYCAP)
    unsigned long long* M         = (unsigned long long*)(W + 3388160);// 2097152 B
    // Aliases into the dead ord region (ord unread after compact):
    unsigned long long* Diag      = (unsigned long long*)(W + 262400); // 32768 B
    int* cIdx                     = (int*)(W + 295168);                // 16384 B
    float* cScore                 = (float*)(W + 311552);              // 16384 B
    int* cLab                     = (int*)(W + 327936);                // 16384 B
    float4* cBox                  = (float4*)(W + 344320);             // 65536 B
    // Aliases into M (M written by k_mask AFTER select/compact are done):
    unsigned* cnt_lin             = (unsigned*)(W + 3388160);          // 262144 B
    unsigned* chunkSum            = (unsigned*)(W + 3650304);          // 4096 B

    int nb = (N_ANCH + 255) / 256;
    int nwb = (N_ANCH + 3) / 4;     // wave-per-anchor decode: 4 anchors/block
    k_zero<<<64, 1024, 0, stream>>>(hist, meta);
    k_decode<<<nwb, 256, 0, stream>>>(pred, ord, lab, box, hist);
    k_unperm<<<64, 1024, 0, stream>>>(hist, cnt_lin, chunkSum);
    k_select0<<<1, 1024, 0, stream>>>(cnt_lin, chunkSum, meta);
    k_compact<<<nb, 256, 0, stream>>>(ord, meta, keys);
    k_rank<<<256, 1024, 0, stream>>>(keys, lab, box, cIdx, cScore, cLab, cBox, meta);
    k_mask<<<1024, 256, 0, stream>>>(cBox, cLab, meta, M, Diag);
    k_nmsfinal<<<1, 256, 0, stream>>>(M, Diag, cScore, cBox, cIdx, pred, img, inp, out, out_size);
}